// Round 1
// baseline (258.199 us; speedup 1.0000x reference)
//
#include <hip/hip_runtime.h>

#define NSAMP 4096
#define KDIM 64
#define NITER 200

// ---------------------------------------------------------------------------
// Setup: inv_item = inv(A^T A + 2*DtD + 5*I) via Woodbury.
// B = 5I + 2*DtD is circulant tridiagonal (diag 9, off-diag -2, wrapped).
// Binv computed in closed form from eigenvalues lam_m = 9 - 4 cos(2 pi m/64).
// inv_item = Binv - Binv A^T (I9 + A Binv A^T)^-1 A Binv
//          = Binv - P^T Sinv P,  P = A Binv (9x64), S = I9 + P A^T (9x9).
// ---------------------------------------------------------------------------
__global__ __launch_bounds__(256) void setup_woodbury(const float* __restrict__ A,
                                                      float* __restrict__ inv_out) {
  __shared__ float binv[64];     // first row of circulant Binv
  __shared__ float P[9][64];
  __shared__ float Q[9][64];
  __shared__ double S[9][9];
  __shared__ double Sinv[9][9];
  __shared__ double W[9][18];
  const int tid = threadIdx.x;
  const double TWO_PI = 6.283185307179586476925286766559;

  // 1. Binv first row (double precision DFT sum; B is SPD, lam in [5,13])
  if (tid < 64) {
    double acc = 0.0;
    for (int m = 0; m < 64; ++m) {
      double th = (TWO_PI / 64.0) * (double)m;
      double lam = 9.0 - 4.0 * cos(th);
      acc += cos(th * (double)tid) / lam;
    }
    binv[tid] = (float)(acc / 64.0);
  }
  __syncthreads();

  // 2. P[m][i] = sum_k A[m][k] * Binv[k][i],  Binv[k][i] = binv[(k-i) mod 64]
  for (int e = tid; e < 9 * 64; e += 256) {
    int m = e >> 6, i = e & 63;
    double acc = 0.0;
    for (int k = 0; k < 64; ++k)
      acc += (double)A[m * 64 + k] * (double)binv[(k - i) & 63];
    P[m][i] = (float)acc;
  }
  __syncthreads();

  // 3. S = I9 + P A^T
  if (tid < 81) {
    int m = tid / 9, n = tid % 9;
    double acc = (m == n) ? 1.0 : 0.0;
    for (int i = 0; i < 64; ++i)
      acc += (double)P[m][i] * (double)A[n * 64 + i];
    S[m][n] = acc;
  }
  __syncthreads();

  // 4. Sinv (9x9, SPD, no pivoting needed), single thread, double precision
  if (tid == 0) {
    for (int r = 0; r < 9; ++r)
      for (int c = 0; c < 9; ++c) {
        W[r][c] = S[r][c];
        W[r][c + 9] = (r == c) ? 1.0 : 0.0;
      }
    for (int k = 0; k < 9; ++k) {
      double ip = 1.0 / W[k][k];
      for (int c = 0; c < 18; ++c) W[k][c] *= ip;
      for (int r = 0; r < 9; ++r)
        if (r != k) {
          double f = W[r][k];
          for (int c = 0; c < 18; ++c) W[r][c] -= f * W[k][c];
        }
    }
    for (int r = 0; r < 9; ++r)
      for (int c = 0; c < 9; ++c) Sinv[r][c] = W[r][c + 9];
  }
  __syncthreads();

  // 5. Q = Sinv P  (9x64)
  for (int e = tid; e < 9 * 64; e += 256) {
    int m = e >> 6, j = e & 63;
    double acc = 0.0;
    for (int n = 0; n < 9; ++n) acc += Sinv[m][n] * (double)P[n][j];
    Q[m][j] = (float)acc;
  }
  __syncthreads();

  // 6. inv_item[i][j] = Binv[i][j] - sum_m P[m][i] * Q[m][j]
  for (int e = tid; e < 64 * 64; e += 256) {
    int i = e >> 6, j = e & 63;
    float acc = binv[(i - j) & 63];
    for (int m = 0; m < 9; ++m) acc = fmaf(-P[m][i], Q[m][j], acc);
    inv_out[e] = acc;
  }
}

// ---------------------------------------------------------------------------
// Main ADMM kernel: one wave (64 lanes) per sample; lane k owns element k.
// inv_item row `lane` lives in 64 VGPRs (loaded once, used 200x).
// D(v)[i] = v[(i+1)%64] - v[i]  -> one __shfl.
// Mat-vec: resid broadcast through per-wave LDS buffer (broadcast reads
// are bank-conflict-free), 64 fp32 FMAs per lane per iteration.
// ---------------------------------------------------------------------------
__global__ __launch_bounds__(256, 4) void admm_kernel(
    const float* __restrict__ target, const float* __restrict__ A,
    const float* __restrict__ x0, const float* __restrict__ invmat,
    float* __restrict__ out) {
  __shared__ float rbuf[4][64];
  const int tid = threadIdx.x;
  const int wid = tid >> 6;
  const int lane = tid & 63;
  const int s = blockIdx.x * 4 + wid;

  // --- ATb = (target_s @ A^T) @ A, via 9 wave-reductions ---
  float t = target[s * 64 + lane];
  float atb = 0.f;
#pragma unroll
  for (int m = 0; m < 9; ++m) {
    float a = A[m * 64 + lane];
    float p = t * a;
#pragma unroll
    for (int off = 32; off; off >>= 1) p += __shfl_xor(p, off, 64);
    atb = fmaf(a, p, atb);  // p is the full dot(target_s, A_m) in every lane
  }

  // --- load inv_item row `lane` into registers ---
  float inv_r[64];
  const float4* ir = reinterpret_cast<const float4*>(invmat + lane * 64);
#pragma unroll
  for (int q = 0; q < 16; ++q) {
    float4 v = ir[q];
    inv_r[4 * q + 0] = v.x;
    inv_r[4 * q + 1] = v.y;
    inv_r[4 * q + 2] = v.z;
    inv_r[4 * q + 3] = v.w;
  }

  float x = x0[s * 64 + lane];
  float eta = 0.f, tau = 0.f;
  const int nxt = (lane + 1) & 63;

  for (int it = 0; it < NITER; ++it) {
    // u_tv = soft_thresh(D(x) + eta/2, 5e-5)
    float xs = __shfl(x, nxt, 64);
    float Dx = xs - x;
    float v = fmaf(eta, 0.5f, Dx);
    float av = fmaxf(fabsf(v) - 5e-5f, 0.f);
    float u = copysignf(av, v);
    // w = max(x + tau/5, 0)
    float w = fmaxf(fmaf(tau, 0.2f, x), 0.f);
    // resid = atb + D(2u - eta) + 5w - tau
    float tv = fmaf(2.f, u, -eta);
    float ts = __shfl(tv, nxt, 64);
    float Dt = ts - tv;
    float resid = fmaf(5.f, w, atb) + Dt - tau;

    rbuf[wid][lane] = resid;
    __syncthreads();

    // x = inv_item @ resid  (lane i: dot(inv row i, resid))
    float acc = 0.f;
#pragma unroll
    for (int j4 = 0; j4 < 16; ++j4) {
      float4 r4 = *reinterpret_cast<const float4*>(&rbuf[wid][j4 * 4]);
      acc = fmaf(inv_r[4 * j4 + 0], r4.x, acc);
      acc = fmaf(inv_r[4 * j4 + 1], r4.y, acc);
      acc = fmaf(inv_r[4 * j4 + 2], r4.z, acc);
      acc = fmaf(inv_r[4 * j4 + 3], r4.w, acc);
    }
    __syncthreads();
    x = acc;

    // eta += 2*(D(x) - u); tau += 5*(x - w)
    float xs2 = __shfl(x, nxt, 64);
    float Dx2 = xs2 - x;
    eta = fmaf(2.f, Dx2 - u, eta);
    tau = fmaf(5.f, x - w, tau);
  }

  out[s * 64 + lane] = x;
}

extern "C" void kernel_launch(void* const* d_in, const int* in_sizes, int n_in,
                              void* d_out, int out_size, void* d_ws, size_t ws_size,
                              hipStream_t stream) {
  const float* target = (const float*)d_in[0];  // (4096, 64)
  const float* A = (const float*)d_in[1];       // (9, 64)
  const float* x0 = (const float*)d_in[2];      // (4096, 64)
  float* out = (float*)d_out;                   // (4096, 64)
  float* inv_ws = (float*)d_ws;                 // 64*64 floats scratch

  setup_woodbury<<<1, 256, 0, stream>>>(A, inv_ws);
  admm_kernel<<<NSAMP / 4, 256, 0, stream>>>(target, A, x0, inv_ws, out);
}